// Round 1
// baseline (424.970 us; speedup 1.0000x reference)
//
#include <hip/hip_runtime.h>

#define HEADS 4
#define NN 256
#define DW 32

// ---------------------------------------------------------------------------
// Kernel A: triangle bias, stored transposed for coalesced reads in attention:
//   bias_t[h][k][j] = x[j][k] . Wb[h] + bb[h]
// block = j (n1), thread = k (n2)
// ---------------------------------------------------------------------------
__global__ __launch_bounds__(256) void bias_kernel(
    const float* __restrict__ x, const float* __restrict__ Wb,
    const float* __restrict__ bb, float* __restrict__ bias_t) {
  const int n1 = blockIdx.x;
  const int n2 = threadIdx.x;
  const float* xr = x + (n1 * NN + n2) * DW;
  float xv[DW];
#pragma unroll
  for (int c = 0; c < DW / 4; ++c) {
    const float4 v = reinterpret_cast<const float4*>(xr)[c];
    xv[c * 4 + 0] = v.x; xv[c * 4 + 1] = v.y;
    xv[c * 4 + 2] = v.z; xv[c * 4 + 3] = v.w;
  }
#pragma unroll
  for (int h = 0; h < HEADS; ++h) {
    float a0 = 0.f, a1 = 0.f;
#pragma unroll
    for (int d = 0; d < DW; d += 2) {
      a0 += xv[d] * Wb[h * DW + d];
      a1 += xv[d + 1] * Wb[h * DW + d + 1];
    }
    bias_t[(h * NN + n2) * NN + n1] = a0 + a1 + bb[h];
  }
}

// ---------------------------------------------------------------------------
// Kernel B: fused QKV projection + attention.
// grid = 512: block handles (i = bid>>1, head pair h0 = (bid&1)*2).
// 256 threads: thread t -> head h = h0 + (t>>7), queries j = (t&127), +128.
// K/V for both heads staged in LDS (fp32), projected in-block from x row i.
// One-pass softmax without max subtraction (scores bounded, fp32-safe;
// masked keys underflow exp() to 0 exactly like the reference's -1e9).
// ---------------------------------------------------------------------------
__global__ __launch_bounds__(256) void attn_kernel(
    const float* __restrict__ x, const float* __restrict__ mask,
    const float* __restrict__ Wq, const float* __restrict__ bq,
    const float* __restrict__ Wk, const float* __restrict__ bk,
    const float* __restrict__ Wv, const float* __restrict__ bv,
    const float* __restrict__ bias_t, float* __restrict__ out) {
  __shared__ float K_lds[2][NN][DW];
  __shared__ float V_lds[2][NN][DW];
  __shared__ float mterm[NN];

  const int bid = blockIdx.x;
  const int i = bid >> 1;
  const int h0 = (bid & 1) * 2;
  const int t = threadIdx.x;
  const int tj = t & 127;
  // wave-uniform head selector -> SGPR, lets W addressing scalarize
  const int th = __builtin_amdgcn_readfirstlane(t >> 7);
  const int h = h0 + th;
  const float scale = 0.17677669529663687f;  // 1/sqrt(32)

  // ---- Q for this thread's two queries (registers only, no sync needed) ----
  float q0[DW], q1[DW];
  {
    float xv[DW];
    const float* wq = Wq + h * DW * DW;
    const float* xr = x + (i * NN + tj) * DW;
#pragma unroll
    for (int c = 0; c < 8; ++c) {
      const float4 v = reinterpret_cast<const float4*>(xr)[c];
      xv[c * 4 + 0] = v.x; xv[c * 4 + 1] = v.y;
      xv[c * 4 + 2] = v.z; xv[c * 4 + 3] = v.w;
    }
#pragma unroll
    for (int d = 0; d < DW; ++d) {
      float a0 = 0.f, a1 = 0.f;
#pragma unroll
      for (int dd = 0; dd < DW; dd += 2) {
        a0 += xv[dd] * wq[d * DW + dd];
        a1 += xv[dd + 1] * wq[d * DW + dd + 1];
      }
      q0[d] = (a0 + a1 + bq[h * DW + d]) * scale;
    }
    const float* xr2 = x + (i * NN + tj + 128) * DW;
#pragma unroll
    for (int c = 0; c < 8; ++c) {
      const float4 v = reinterpret_cast<const float4*>(xr2)[c];
      xv[c * 4 + 0] = v.x; xv[c * 4 + 1] = v.y;
      xv[c * 4 + 2] = v.z; xv[c * 4 + 3] = v.w;
    }
#pragma unroll
    for (int d = 0; d < DW; ++d) {
      float a0 = 0.f, a1 = 0.f;
#pragma unroll
      for (int dd = 0; dd < DW; dd += 2) {
        a0 += xv[dd] * wq[d * DW + dd];
        a1 += xv[dd + 1] * wq[d * DW + dd + 1];
      }
      q1[d] = (a0 + a1 + bq[h * DW + d]) * scale;
    }
  }

  // ---- project K,V row kk = t for BOTH heads of this pair into LDS ----
  {
    float xv[DW];
    const float* xr = x + (i * NN + t) * DW;
#pragma unroll
    for (int c = 0; c < 8; ++c) {
      const float4 v = reinterpret_cast<const float4*>(xr)[c];
      xv[c * 4 + 0] = v.x; xv[c * 4 + 1] = v.y;
      xv[c * 4 + 2] = v.z; xv[c * 4 + 3] = v.w;
    }
#pragma unroll 1
    for (int hh = 0; hh < 2; ++hh) {
      const int hcur = h0 + hh;
#pragma unroll 1
      for (int m = 0; m < 2; ++m) {
        const float* W = (m == 0) ? Wk : Wv;
        const float* bvec = (m == 0) ? bk : bv;
        float* dst = (m == 0) ? &K_lds[hh][t][0] : &V_lds[hh][t][0];
#pragma unroll 1
        for (int c = 0; c < 8; ++c) {
          float f[4];
#pragma unroll
          for (int e = 0; e < 4; ++e) {
            const int d = c * 4 + e;
            const float* wr = W + (hcur * DW + d) * DW;
            float a0 = 0.f, a1 = 0.f;
#pragma unroll
            for (int dd = 0; dd < DW; dd += 2) {
              a0 += xv[dd] * wr[dd];
              a1 += xv[dd + 1] * wr[dd + 1];
            }
            f[e] = a0 + a1 + bvec[hcur * DW + d];
          }
          *reinterpret_cast<float4*>(dst + c * 4) =
              make_float4(f[0], f[1], f[2], f[3]);
        }
      }
    }
  }
  mterm[t] = (mask[i * NN + t] - 1.0f) * 1e9f;
  __syncthreads();

  // ---- attention over keys ----
  float acc0[DW], acc1[DW];
#pragma unroll
  for (int d = 0; d < DW; ++d) { acc0[d] = 0.f; acc1[d] = 0.f; }
  float l0 = 0.f, l1 = 0.f;

  const float* brow = bias_t + (h * NN) * NN;
  float b0 = brow[tj];
  float b1 = brow[tj + 128];

  for (int kk = 0; kk < NN; ++kk) {
    // prefetch next iteration's bias (wraps at the end; value unused then)
    const int kn = (kk + 1) & (NN - 1);
    const float nb0 = brow[kn * NN + tj];
    const float nb1 = brow[kn * NN + tj + 128];
    const float mt = mterm[kk];

    float kr[DW];
#pragma unroll
    for (int c = 0; c < 8; ++c) {
      const float4 v = *reinterpret_cast<const float4*>(&K_lds[th][kk][c * 4]);
      kr[c * 4 + 0] = v.x; kr[c * 4 + 1] = v.y;
      kr[c * 4 + 2] = v.z; kr[c * 4 + 3] = v.w;
    }
    float d0a = 0.f, d0b = 0.f, d1a = 0.f, d1b = 0.f;
#pragma unroll
    for (int dd = 0; dd < DW; dd += 2) {
      d0a += q0[dd] * kr[dd];
      d0b += q0[dd + 1] * kr[dd + 1];
      d1a += q1[dd] * kr[dd];
      d1b += q1[dd + 1] * kr[dd + 1];
    }
    const float s0 = d0a + d0b + b0 + mt;
    const float s1 = d1a + d1b + b1 + mt;
    const float p0 = __expf(s0);
    const float p1 = __expf(s1);
    l0 += p0;
    l1 += p1;
#pragma unroll
    for (int c = 0; c < 8; ++c) {
      const float4 v = *reinterpret_cast<const float4*>(&V_lds[th][kk][c * 4]);
      acc0[c * 4 + 0] += p0 * v.x; acc0[c * 4 + 1] += p0 * v.y;
      acc0[c * 4 + 2] += p0 * v.z; acc0[c * 4 + 3] += p0 * v.w;
      acc1[c * 4 + 0] += p1 * v.x; acc1[c * 4 + 1] += p1 * v.y;
      acc1[c * 4 + 2] += p1 * v.z; acc1[c * 4 + 3] += p1 * v.w;
    }
    b0 = nb0;
    b1 = nb1;
  }

  const float r0 = 1.0f / l0;
  const float r1 = 1.0f / l1;
  float* o0 = out + ((i * NN + tj) * HEADS + h) * DW;
  float* o1 = out + ((i * NN + tj + 128) * HEADS + h) * DW;
#pragma unroll
  for (int c = 0; c < 8; ++c) {
    *reinterpret_cast<float4*>(&o0[c * 4]) =
        make_float4(acc0[c * 4] * r0, acc0[c * 4 + 1] * r0,
                    acc0[c * 4 + 2] * r0, acc0[c * 4 + 3] * r0);
    *reinterpret_cast<float4*>(&o1[c * 4]) =
        make_float4(acc1[c * 4] * r1, acc1[c * 4 + 1] * r1,
                    acc1[c * 4 + 2] * r1, acc1[c * 4 + 3] * r1);
  }
}

extern "C" void kernel_launch(void* const* d_in, const int* in_sizes, int n_in,
                              void* d_out, int out_size, void* d_ws,
                              size_t ws_size, hipStream_t stream) {
  const float* x    = (const float*)d_in[0];
  const float* mask = (const float*)d_in[1];
  const float* Wq   = (const float*)d_in[2];
  const float* bq   = (const float*)d_in[3];
  const float* Wk   = (const float*)d_in[4];
  const float* bk   = (const float*)d_in[5];
  const float* Wv   = (const float*)d_in[6];
  const float* bv   = (const float*)d_in[7];
  const float* Wb   = (const float*)d_in[8];
  const float* bb   = (const float*)d_in[9];
  float* out = (float*)d_out;
  float* bias_t = (float*)d_ws;  // HEADS*NN*NN floats = 1 MB

  bias_kernel<<<NN, NN, 0, stream>>>(x, Wb, bb, bias_t);
  attn_kernel<<<NN * 2, 256, 0, stream>>>(x, mask, Wq, bq, Wk, bk, Wv, bv,
                                          bias_t, out);
}

// Round 2
// 164.887 us; speedup vs baseline: 2.5773x; 2.5773x over previous
//
#include <hip/hip_runtime.h>

#define HEADS 4
#define NN 256
#define DW 32

typedef __bf16 bf16x8 __attribute__((ext_vector_type(8)));
typedef float f32x4 __attribute__((ext_vector_type(4)));

static __device__ __forceinline__ ushort f2bf(float f) {
  __bf16 h = (__bf16)f;
  ushort r;
  __builtin_memcpy(&r, &h, 2);
  return r;
}

// ---------------------------------------------------------------------------
// Triangle bias: bias[h][j][k] = x[0,j,k,:] . Wb[h] + bb[h]   (1 MB in d_ws)
// ---------------------------------------------------------------------------
__global__ __launch_bounds__(256) void bias_kernel(
    const float* __restrict__ x, const float* __restrict__ Wb,
    const float* __restrict__ bb, float* __restrict__ bias) {
  const int j = blockIdx.x;
  const int k = threadIdx.x;
  const float* xr = x + (j * NN + k) * DW;
  float xv[DW];
#pragma unroll
  for (int c = 0; c < 8; ++c) {
    const float4 v = reinterpret_cast<const float4*>(xr)[c];
    xv[c * 4 + 0] = v.x; xv[c * 4 + 1] = v.y;
    xv[c * 4 + 2] = v.z; xv[c * 4 + 3] = v.w;
  }
#pragma unroll
  for (int h = 0; h < HEADS; ++h) {
    float a0 = 0.f, a1 = 0.f;
#pragma unroll
    for (int d = 0; d < DW; d += 2) {
      a0 += xv[d] * Wb[h * DW + d];
      a1 += xv[d + 1] * Wb[h * DW + d + 1];
    }
    bias[(h * NN + j) * NN + k] = a0 + a1 + bb[h];
  }
}

// ---------------------------------------------------------------------------
// Fused QKV projection + attention, bf16 MFMA (16x16x32).
// grid = 1024: block = (i = bid>>2, h = bid&3). 4 waves, wave w owns
// queries 64w..64w+63. One-pass softmax (no max subtraction; p *= mask).
//
// Fragment conventions (mfma_f32_16x16x32_bf16):
//   A frag: lane holds A[l%16][8*(l/16)+jj], jj=0..7
//   B frag: lane holds B[8*(l/16)+jj][l%16]
//   C/D   : lane holds D[(l>>4)*4+j][l&15]   (HW-verified layout)
// LDS strides (shorts): Qs/Ks/Ps = 40 (80B, 16B-aligned, <=2-way banks),
// Vt = 264 (528B).
// ---------------------------------------------------------------------------
__global__ __launch_bounds__(256) void attn_mfma(
    const float* __restrict__ x, const float* __restrict__ mask,
    const float* __restrict__ Wq, const float* __restrict__ bq,
    const float* __restrict__ Wk, const float* __restrict__ bk,
    const float* __restrict__ Wv, const float* __restrict__ bv,
    const float* __restrict__ bias, float* __restrict__ out) {
  __shared__ ushort Qs[NN][40];      // [query][dim]
  __shared__ ushort Ks[NN][40];      // [key][dim]
  __shared__ ushort Vt[DW][264];     // [dim][key]  (transposed)
  __shared__ ushort Ps[4][64][40];   // per-wave P scratch [q][key-in-block]
  __shared__ float mk[NN];

  const int bid = blockIdx.x;
  const int i = bid >> 2;
  const int h = bid & 3;
  const int t = threadIdx.x;
  const int w = t >> 6;
  const int l = t & 63;
  const int lr = l & 15;   // A-row / B-col / C-col
  const int lq = l >> 4;   // lane quarter
  const int rowbase = w * 64;
  const float scale = 0.17677669529663687f;  // 1/sqrt(32)

  // ---- W B-fragments for Q,K,V (held in regs during projection) ----
  bf16x8 wqf[2], wkf[2], wvf[2];
#pragma unroll
  for (int nt = 0; nt < 2; ++nt) {
    const int dd = nt * 16 + lr;  // output dim 0..31
    const float* rq = Wq + (h * DW + dd) * DW + lq * 8;
    const float* rk = Wk + (h * DW + dd) * DW + lq * 8;
    const float* rv = Wv + (h * DW + dd) * DW + lq * 8;
#pragma unroll
    for (int jj = 0; jj < 8; ++jj) {
      wqf[nt][jj] = (__bf16)rq[jj];
      wkf[nt][jj] = (__bf16)rk[jj];
      wvf[nt][jj] = (__bf16)rv[jj];
    }
  }

  // ---- project this wave's 64 rows of Q,K,V into LDS ----
#pragma unroll
  for (int rt = 0; rt < 4; ++rt) {
    const float* xr = x + (i * NN + rowbase + rt * 16 + lr) * DW + lq * 8;
    bf16x8 af;
#pragma unroll
    for (int jj = 0; jj < 8; ++jj) af[jj] = (__bf16)xr[jj];
#pragma unroll
    for (int nt = 0; nt < 2; ++nt) {
      const int dd = nt * 16 + lr;
      f32x4 z = {0.f, 0.f, 0.f, 0.f};
      f32x4 cq = __builtin_amdgcn_mfma_f32_16x16x32_bf16(af, wqf[nt], z, 0, 0, 0);
      f32x4 ck = __builtin_amdgcn_mfma_f32_16x16x32_bf16(af, wkf[nt], z, 0, 0, 0);
      f32x4 cv = __builtin_amdgcn_mfma_f32_16x16x32_bf16(af, wvf[nt], z, 0, 0, 0);
      const float bqv = bq[h * DW + dd];
      const float bkv = bk[h * DW + dd];
      const float bvv = bv[h * DW + dd];
#pragma unroll
      for (int j = 0; j < 4; ++j) {
        const int r2 = rowbase + rt * 16 + lq * 4 + j;
        Qs[r2][dd] = f2bf((cq[j] + bqv) * scale);  // fold 1/sqrt(D) into Q
        Ks[r2][dd] = f2bf(ck[j] + bkv);
        Vt[dd][r2] = f2bf(cv[j] + bvv);
      }
    }
  }
  mk[t] = mask[i * NN + t];
  __syncthreads();

  // ---- hoisted Q A-fragments (reused for all key blocks) ----
  bf16x8 qf[4];
#pragma unroll
  for (int qt = 0; qt < 4; ++qt)
    qf[qt] = *(const bf16x8*)&Qs[rowbase + qt * 16 + lr][lq * 8];

  f32x4 co[4][2];
  float lsum[4][4];
#pragma unroll
  for (int qt = 0; qt < 4; ++qt) {
#pragma unroll
    for (int nt = 0; nt < 2; ++nt) co[qt][nt] = (f32x4){0.f, 0.f, 0.f, 0.f};
#pragma unroll
    for (int j = 0; j < 4; ++j) lsum[qt][j] = 0.f;
  }

  const float* biasrow = bias + (h * NN) * NN;  // [q][key]

  for (int kb = 0; kb < 8; ++kb) {
    const int kbase = kb * 32;
    // K B-frags for this key block
    bf16x8 kf[2];
#pragma unroll
    for (int kt = 0; kt < 2; ++kt)
      kf[kt] = *(const bf16x8*)&Ks[kbase + kt * 16 + lr][lq * 8];

    // scores: S[q][key], 4 q-tiles x 2 k-tiles
    f32x4 s[4][2];
#pragma unroll
    for (int qt = 0; qt < 4; ++qt)
#pragma unroll
      for (int kt = 0; kt < 2; ++kt) {
        f32x4 z = {0.f, 0.f, 0.f, 0.f};
        s[qt][kt] = __builtin_amdgcn_mfma_f32_16x16x32_bf16(qf[qt], kf[kt], z, 0, 0, 0);
      }

    const float mv0 = mk[kbase + lr];
    const float mv1 = mk[kbase + 16 + lr];

    // softmax numerator + P -> LDS (wave-private, no barrier needed)
#pragma unroll
    for (int qt = 0; qt < 4; ++qt)
#pragma unroll
      for (int kt = 0; kt < 2; ++kt) {
        const int key = kbase + kt * 16 + lr;
        const float mv = kt ? mv1 : mv0;
#pragma unroll
        for (int j = 0; j < 4; ++j) {
          const int q = rowbase + qt * 16 + lq * 4 + j;
          const float p = __expf(s[qt][kt][j] + biasrow[q * NN + key]) * mv;
          lsum[qt][j] += p;
          Ps[w][qt * 16 + lq * 4 + j][kt * 16 + lr] = f2bf(p);
        }
      }

    // PV: A = P (re-read in A-layout), B = V (from transposed store)
    bf16x8 vf[2];
#pragma unroll
    for (int nt = 0; nt < 2; ++nt)
      vf[nt] = *(const bf16x8*)&Vt[nt * 16 + lr][kbase + lq * 8];
    bf16x8 pf[4];
#pragma unroll
    for (int qt = 0; qt < 4; ++qt)
      pf[qt] = *(const bf16x8*)&Ps[w][qt * 16 + lr][lq * 8];
#pragma unroll
    for (int qt = 0; qt < 4; ++qt)
#pragma unroll
      for (int nt = 0; nt < 2; ++nt)
        co[qt][nt] =
            __builtin_amdgcn_mfma_f32_16x16x32_bf16(pf[qt], vf[nt], co[qt][nt], 0, 0, 0);
  }

  // ---- denominators: reduce lsum across the 16 lanes of each row group ----
  float rs[4][4];
#pragma unroll
  for (int qt = 0; qt < 4; ++qt)
#pragma unroll
    for (int j = 0; j < 4; ++j) {
      float v = lsum[qt][j];
      v += __shfl_xor(v, 1);
      v += __shfl_xor(v, 2);
      v += __shfl_xor(v, 4);
      v += __shfl_xor(v, 8);
      rs[qt][j] = 1.0f / v;
    }

  // ---- normalize + store: out[i][q][h][d] ----
#pragma unroll
  for (int qt = 0; qt < 4; ++qt)
#pragma unroll
    for (int nt = 0; nt < 2; ++nt) {
      const int dd = nt * 16 + lr;
#pragma unroll
      for (int j = 0; j < 4; ++j) {
        const int q = rowbase + qt * 16 + lq * 4 + j;
        out[((i * NN + q) * HEADS + h) * DW + dd] = co[qt][nt][j] * rs[qt][j];
      }
    }
}

extern "C" void kernel_launch(void* const* d_in, const int* in_sizes, int n_in,
                              void* d_out, int out_size, void* d_ws,
                              size_t ws_size, hipStream_t stream) {
  const float* x    = (const float*)d_in[0];
  const float* mask = (const float*)d_in[1];
  const float* Wq   = (const float*)d_in[2];
  const float* bq   = (const float*)d_in[3];
  const float* Wk   = (const float*)d_in[4];
  const float* bk   = (const float*)d_in[5];
  const float* Wv   = (const float*)d_in[6];
  const float* bv   = (const float*)d_in[7];
  const float* Wb   = (const float*)d_in[8];
  const float* bb   = (const float*)d_in[9];
  float* out = (float*)d_out;
  float* bias = (float*)d_ws;  // HEADS*NN*NN floats = 1 MB

  bias_kernel<<<NN, 256, 0, stream>>>(x, Wb, bb, bias);
  attn_mfma<<<NN * HEADS, 256, 0, stream>>>(x, mask, Wq, bq, Wk, bk, Wv, bv,
                                            bias, out);
}

// Round 3
// 118.432 us; speedup vs baseline: 3.5883x; 1.3922x over previous
//
#include <hip/hip_runtime.h>

#define HEADS 4
#define NN 256
#define DW 32

typedef __bf16 bf16x8 __attribute__((ext_vector_type(8)));
typedef float f32x4 __attribute__((ext_vector_type(4)));
typedef float f32x16 __attribute__((ext_vector_type(16)));
typedef unsigned int u32x4 __attribute__((ext_vector_type(4)));
typedef unsigned short ushort4v __attribute__((ext_vector_type(4)));

static __device__ __forceinline__ ushort f2bf(float f) {
  __bf16 h = (__bf16)f;
  ushort r;
  __builtin_memcpy(&r, &h, 2);
  return r;
}

static __device__ __forceinline__ unsigned cvt_pk_bf16(float lo, float hi) {
  unsigned r;
  asm("v_cvt_pk_bf16_f32 %0, %1, %2" : "=v"(r) : "v"(lo), "v"(hi));
  return r;
}

// ---------------------------------------------------------------------------
// Triangle bias, TRANSPOSED for the swapped-QK attention kernel:
//   bias_t[h][k][j] = x[0,j,k,:] . Wb[h] + bb[h]
// block = j, thread = k. Reads coalesced; writes scattered (1 MB total, ok).
// ---------------------------------------------------------------------------
__global__ __launch_bounds__(256) void bias_kernel(
    const float* __restrict__ x, const float* __restrict__ Wb,
    const float* __restrict__ bb, float* __restrict__ bias_t) {
  const int j = blockIdx.x;
  const int k = threadIdx.x;
  const float* xr = x + (j * NN + k) * DW;
  float xv[DW];
#pragma unroll
  for (int c = 0; c < 8; ++c) {
    const float4 v = reinterpret_cast<const float4*>(xr)[c];
    xv[c * 4 + 0] = v.x; xv[c * 4 + 1] = v.y;
    xv[c * 4 + 2] = v.z; xv[c * 4 + 3] = v.w;
  }
#pragma unroll
  for (int h = 0; h < HEADS; ++h) {
    float a0 = 0.f, a1 = 0.f;
#pragma unroll
    for (int d = 0; d < DW; d += 2) {
      a0 += xv[d] * Wb[h * DW + d];
      a1 += xv[d + 1] * Wb[h * DW + d + 1];
    }
    bias_t[(h * NN + k) * NN + j] = a0 + a1 + bb[h];
  }
}

// ---------------------------------------------------------------------------
// Fused QKV projection + attention, swapped-QK 32x32x16 MFMA structure.
// grid = 1024: block = (i = bid>>2, h = bid&3). 4 waves, wave w owns
// queries 64w..64w+63 as two 32-row tiles.
//
// S^T = K·Q^T  (A = K[32key x 16d], B = Q^T[16d x 32q]) -> C-layout gives
// lane l: q = l&31, 16 key values at key=(r&3)+8*(r>>2)+4*(l>>5).
// Softmax is lane-local. P fragments for O = P·V are built in-register with
// cvt_pk_bf16 + v_permlane32_swap. O C-layout cols = d -> coalesced stores.
//
// LDS: Kq[256][40] (Q staged first, then K after a barrier), Vt[32][264]
// (V transposed), mk, Ls. Strides 20/132 dwords == 4 (mod 8): conflict-free
// b128 reads for 32-consecutive-row access. No barriers in the main loop.
// ---------------------------------------------------------------------------
__global__ __launch_bounds__(256, 3) void attn_mfma(
    const float* __restrict__ x, const float* __restrict__ mask,
    const float* __restrict__ Wq, const float* __restrict__ bq,
    const float* __restrict__ Wk, const float* __restrict__ bk,
    const float* __restrict__ Wv, const float* __restrict__ bv,
    const float* __restrict__ bias_t, float* __restrict__ out) {
  __shared__ ushort Kq[NN][40];
  __shared__ ushort Vt[DW][264];
  __shared__ float mk[NN];
  __shared__ float Ls[NN];

  const int bid = blockIdx.x;
  const int i = bid >> 2;
  const int h = bid & 3;
  const int t = threadIdx.x;
  const int w = t >> 6;
  const int l = t & 63;
  const int lo5 = l & 31;
  const int hi = l >> 5;
  const int lr = l & 15;
  const int lq = l >> 4;
  const int rowbase = w * 64;
  const float scale = 0.17677669529663687f;  // 1/sqrt(32)

  // ---- W B-fragments (16x16x32 layout) for Q,K,V projections ----
  bf16x8 wqf[2], wkf[2], wvf[2];
#pragma unroll
  for (int nt = 0; nt < 2; ++nt) {
    const int dd = nt * 16 + lr;
    const float* rq = Wq + (h * DW + dd) * DW + lq * 8;
    const float* rk = Wk + (h * DW + dd) * DW + lq * 8;
    const float* rv = Wv + (h * DW + dd) * DW + lq * 8;
#pragma unroll
    for (int jj = 0; jj < 8; ++jj) {
      wqf[nt][jj] = (__bf16)rq[jj];
      wkf[nt][jj] = (__bf16)rk[jj];
      wvf[nt][jj] = (__bf16)rv[jj];
    }
  }

  // ---- x A-fragments for this wave's 64 rows (reused for Q,K,V) ----
  bf16x8 af[4];
#pragma unroll
  for (int rt = 0; rt < 4; ++rt) {
    const float* xr = x + (i * NN + rowbase + rt * 16 + lr) * DW + lq * 8;
#pragma unroll
    for (int jj = 0; jj < 8; ++jj) af[rt][jj] = (__bf16)xr[jj];
  }

  // ---- stage Q into Kq, read own B-frags, then overwrite with K ----
#pragma unroll
  for (int rt = 0; rt < 4; ++rt) {
#pragma unroll
    for (int nt = 0; nt < 2; ++nt) {
      const int dd = nt * 16 + lr;
      f32x4 z = {0.f, 0.f, 0.f, 0.f};
      f32x4 cq = __builtin_amdgcn_mfma_f32_16x16x32_bf16(af[rt], wqf[nt], z, 0, 0, 0);
      const float bqv = bq[h * DW + dd];
#pragma unroll
      for (int j = 0; j < 4; ++j)
        Kq[rowbase + rt * 16 + lq * 4 + j][dd] = f2bf((cq[j] + bqv) * scale);
    }
  }
  // own-wave write->read: compiler inserts lgkmcnt wait
  bf16x8 qb[2][2];
#pragma unroll
  for (int qt = 0; qt < 2; ++qt)
#pragma unroll
    for (int dh = 0; dh < 2; ++dh)
      qb[qt][dh] = *(const bf16x8*)&Kq[rowbase + qt * 32 + lo5][dh * 16 + 8 * hi];
  __syncthreads();  // all waves done reading Q from Kq

#pragma unroll
  for (int rt = 0; rt < 4; ++rt) {
#pragma unroll
    for (int nt = 0; nt < 2; ++nt) {
      const int dd = nt * 16 + lr;
      f32x4 z = {0.f, 0.f, 0.f, 0.f};
      f32x4 ck = __builtin_amdgcn_mfma_f32_16x16x32_bf16(af[rt], wkf[nt], z, 0, 0, 0);
      f32x4 cv = __builtin_amdgcn_mfma_f32_16x16x32_bf16(af[rt], wvf[nt], z, 0, 0, 0);
      const float bkv = bk[h * DW + dd];
      const float bvv = bv[h * DW + dd];
#pragma unroll
      for (int j = 0; j < 4; ++j)
        Kq[rowbase + rt * 16 + lq * 4 + j][dd] = f2bf(ck[j] + bkv);
      ushort4v v4;
#pragma unroll
      for (int j = 0; j < 4; ++j) v4[j] = f2bf(cv[j] + bvv);
      *(ushort4v*)&Vt[dd][rowbase + rt * 16 + lq * 4] = v4;
    }
  }
  mk[t] = mask[i * NN + t];
  __syncthreads();

  // ---- main loop over 8 key-blocks of 32; no barriers inside ----
  f32x16 ot[2];
  float lsum[2] = {0.f, 0.f};
#pragma unroll
  for (int qt = 0; qt < 2; ++qt)
#pragma unroll
    for (int r = 0; r < 16; ++r) ot[qt][r] = 0.f;

  const float* bbase = bias_t + (h * NN) * NN;  // [key][q]

  for (int kb = 0; kb < 8; ++kb) {
    const int kbase = kb * 32;
    // mask values for this key block (lane-broadcast LDS reads)
    float mv[16];
#pragma unroll
    for (int r = 0; r < 16; ++r)
      mv[r] = mk[kbase + (r & 3) + 8 * (r >> 2) + 4 * hi];

    const bf16x8 ka0 = *(const bf16x8*)&Kq[kbase + lo5][8 * hi];
    const bf16x8 ka1 = *(const bf16x8*)&Kq[kbase + lo5][16 + 8 * hi];
    const bf16x8 va0 = *(const bf16x8*)&Vt[lo5][kbase + 8 * hi];
    const bf16x8 va1 = *(const bf16x8*)&Vt[lo5][kbase + 16 + 8 * hi];

#pragma unroll
    for (int qt = 0; qt < 2; ++qt) {
      const int qrow = rowbase + qt * 32 + lo5;
      // bias loads (coalesced along q), issued before the MFMAs consume them
      float bi[16];
      const float* bp = bbase + (kbase + 4 * hi) * NN + qrow;
#pragma unroll
      for (int r = 0; r < 16; ++r)
        bi[r] = bp[((r & 3) + 8 * (r >> 2)) * NN];

      f32x16 st;
      {
        f32x16 z;
#pragma unroll
        for (int r = 0; r < 16; ++r) z[r] = 0.f;
        st = __builtin_amdgcn_mfma_f32_32x32x16_bf16(ka0, qb[qt][0], z, 0, 0, 0);
        st = __builtin_amdgcn_mfma_f32_32x32x16_bf16(ka1, qb[qt][1], st, 0, 0, 0);
      }

      float pm[16];
      float ls = 0.f;
#pragma unroll
      for (int r = 0; r < 16; ++r) {
        const float p = __expf(st[r] + bi[r]) * mv[r];
        pm[r] = p;
        ls += p;
      }
      lsum[qt] += ls;

      // P -> A-fragments: cvt_pk pairs + permlane32_swap
#pragma unroll
      for (int half = 0; half < 2; ++half) {
        const int b0 = half * 8;
        unsigned w0, w1, w2, w3;
        {
          unsigned A = cvt_pk_bf16(pm[b0 + 0], pm[b0 + 1]);
          unsigned B = cvt_pk_bf16(pm[b0 + 4], pm[b0 + 5]);
          asm volatile("v_permlane32_swap_b32 %0, %1" : "+v"(A), "+v"(B));
          w0 = A; w2 = B;
        }
        {
          unsigned A = cvt_pk_bf16(pm[b0 + 2], pm[b0 + 3]);
          unsigned B = cvt_pk_bf16(pm[b0 + 6], pm[b0 + 7]);
          asm volatile("v_permlane32_swap_b32 %0, %1" : "+v"(A), "+v"(B));
          w1 = A; w3 = B;
        }
        u32x4 words = {w0, w1, w2, w3};
        const bf16x8 pf = __builtin_bit_cast(bf16x8, words);
        ot[qt] = __builtin_amdgcn_mfma_f32_32x32x16_bf16(
            pf, half ? va1 : va0, ot[qt], 0, 0, 0);
      }
    }
  }

  // ---- denominators: lane-local + cross-half add, broadcast via LDS ----
#pragma unroll
  for (int qt = 0; qt < 2; ++qt) {
    const float ls = lsum[qt] + __shfl_xor(lsum[qt], 32);
    Ls[rowbase + qt * 32 + lo5] = 1.0f / ls;  // both halves write same value
  }

  // ---- normalize + store (C-layout cols = d -> coalesced 128B segments) ----
#pragma unroll
  for (int qt = 0; qt < 2; ++qt)
#pragma unroll
    for (int r = 0; r < 16; ++r) {
      const int qp = (r & 3) + 8 * (r >> 2) + 4 * hi;
      const int qrow = rowbase + qt * 32 + qp;
      out[((i * NN + qrow) * HEADS + h) * DW + lo5] = ot[qt][r] * Ls[qrow];
    }
}

extern "C" void kernel_launch(void* const* d_in, const int* in_sizes, int n_in,
                              void* d_out, int out_size, void* d_ws,
                              size_t ws_size, hipStream_t stream) {
  const float* x    = (const float*)d_in[0];
  const float* mask = (const float*)d_in[1];
  const float* Wq   = (const float*)d_in[2];
  const float* bq   = (const float*)d_in[3];
  const float* Wk   = (const float*)d_in[4];
  const float* bk   = (const float*)d_in[5];
  const float* Wv   = (const float*)d_in[6];
  const float* bv   = (const float*)d_in[7];
  const float* Wb   = (const float*)d_in[8];
  const float* bb   = (const float*)d_in[9];
  float* out = (float*)d_out;
  float* bias_t = (float*)d_ws;  // HEADS*NN*NN floats = 1 MB

  bias_kernel<<<NN, 256, 0, stream>>>(x, Wb, bb, bias_t);
  attn_mfma<<<NN * HEADS, 256, 0, stream>>>(x, mask, Wq, bq, Wk, bk, Wv, bv,
                                            bias_t, out);
}